// Round 13
// baseline (147.219 us; speedup 1.0000x reference)
//
#include <hip/hip_runtime.h>
#include <hip/hip_bf16.h>
#include <math.h>

#define D_MODEL 1024
#define NH      16
#define DK      64
#define SEQ     2048
#define BATCH   2

typedef float  f32x4  __attribute__((ext_vector_type(4)));
typedef __bf16 bf16x8 __attribute__((ext_vector_type(8)));
typedef unsigned short ushx4 __attribute__((ext_vector_type(4)));
typedef unsigned short ushx8 __attribute__((ext_vector_type(8)));
typedef unsigned short u16;

// RNE float->bf16 via compiler cast (single v_cvt on gfx950)
__device__ inline u16 cbf(float f) { __bf16 h = (__bf16)f; return *(u16*)&h; }

__device__ inline void gload16(const u16* g, u16* l) {
    // direct global->LDS DMA, 16B/lane, dest = wave-uniform base + lane*16
    __builtin_amdgcn_global_load_lds(
        (const __attribute__((address_space(1))) unsigned int*)g,
        (__attribute__((address_space(3))) unsigned int*)l,
        16, 0, 0);
}

// ---------------- RoPE tables + work-queue counter zero ----------------
__global__ void rope_tables_kernel(float2* __restrict__ cs, int* __restrict__ counter) {
    if (blockIdx.x == 0 && threadIdx.x == 0) *counter = 0;   // attn queue reset (every call)
    int i = blockIdx.x * 256 + threadIdx.x;      // 2048*32 = 65536 total
    int pos = i >> 5, k = i & 31;
    float inv = powf(10000.0f, -2.0f * (float)k / 64.0f);
    float ang = (float)pos * inv;
    cs[i] = make_float2(cosf(ang), sinf(ang));
}

// ---------------- fp32 -> bf16 converts ----------------
__global__ void cvt_kernel(const float* __restrict__ in, u16* __restrict__ out) {
    size_t i = ((size_t)blockIdx.x * 256 + threadIdx.x) * 8;
    f32x4 v0 = *(const f32x4*)(in + i);
    f32x4 v1 = *(const f32x4*)(in + i + 4);
    ushx4 o0, o1;
    #pragma unroll
    for (int e = 0; e < 4; e++) { o0[e] = cbf(v0[e]); o1[e] = cbf(v1[e]); }
    *(ushx4*)(out + i) = o0;
    *(ushx4*)(out + i + 4) = o1;
}

__global__ void cvtw_kernel(const float* __restrict__ wq, const float* __restrict__ wk,
                            const float* __restrict__ wv, const float* __restrict__ wo,
                            u16* __restrict__ oq, u16* __restrict__ ok,
                            u16* __restrict__ ov, u16* __restrict__ oo) {
    const float* in; u16* out;
    switch (blockIdx.y) {
        case 0: in = wq; out = oq; break;
        case 1: in = wk; out = ok; break;
        case 2: in = wv; out = ov; break;
        default: in = wo; out = oo; break;
    }
    size_t i = ((size_t)blockIdx.x * 256 + threadIdx.x) * 8;
    f32x4 v0 = *(const f32x4*)(in + i);
    f32x4 v1 = *(const f32x4*)(in + i + 4);
    ushx4 o0, o1;
    #pragma unroll
    for (int e = 0; e < 4; e++) { o0[e] = cbf(v0[e]); o1[e] = cbf(v1[e]); }
    *(ushx4*)(out + i) = o0;
    *(ushx4*)(out + i + 4) = o1;
}

// ---------------- GEMM C[m][n] = sum_k A[m][k] W[n][k], 2-phase dbuf (T3-minimum) ----------------
// MODE 0: n in [0,2048): RoPE epilogue -> Qo (pre-scaled 0.125*log2e) / Ko, bf16 [b][h][s][dk]
// MODE 2: fp32 out [m][n]
// MODE 3: swapped operands (rows=n, cols=m) -> coalesced V^T store, bf16 [b][h][dk][s]
template<int MODE>
__global__ __launch_bounds__(256) void gemm_bt(
    const u16* __restrict__ A, const u16* __restrict__ W,
    u16* __restrict__ Qo, u16* __restrict__ Ko, void* __restrict__ Oo,
    const int* __restrict__ tpos, const float2* __restrict__ cs)
{
    constexpr int K = 1024;
    __shared__ u16 As[2][128 * 32];
    __shared__ u16 Bs[2][128 * 32];

    const int t  = threadIdx.x;
    const int m0 = blockIdx.x * 128, n0 = blockIdx.y * 128;
    const int lane = t & 63, wid = t >> 6;
    const int wm = wid >> 1, wn = wid & 1;       // 2x2 wave grid, 64x64 per wave
    const int lr = lane & 15, lg = lane >> 4;

    const int ldrow0 = wid * 32 + (lane >> 2);
    const int ldrow1 = ldrow0 + 16;
    const int lc = lane & 3;
    const u16* Asrc0 = A + (size_t)(m0 + ldrow0) * K + ((lc ^ ((ldrow0 >> 1) & 3)) << 3);
    const u16* Asrc1 = A + (size_t)(m0 + ldrow1) * K + ((lc ^ ((ldrow1 >> 1) & 3)) << 3);
    const u16* Bsrc0 = W + (size_t)(n0 + ldrow0) * K + ((lc ^ ((ldrow0 >> 1) & 3)) << 3);
    const u16* Bsrc1 = W + (size_t)(n0 + ldrow1) * K + ((lc ^ ((ldrow1 >> 1) & 3)) << 3);
    const int d0 = (wid * 32) * 32, d1 = (wid * 32 + 16) * 32;

    f32x4 acc[4][4];
    #pragma unroll
    for (int i = 0; i < 4; i++)
        #pragma unroll
        for (int j2 = 0; j2 < 4; j2++) acc[i][j2] = 0.0f;

    auto stage = [&](int buf, int k0) {
        gload16(Asrc0 + k0, &As[buf][d0]);
        gload16(Asrc1 + k0, &As[buf][d1]);
        gload16(Bsrc0 + k0, &Bs[buf][d0]);
        gload16(Bsrc1 + k0, &Bs[buf][d1]);
    };

    stage(0, 0);
    int buf = 0;
    for (int k0 = 0; k0 < K; k0 += 32) {
        __syncthreads();                 // drains my stage gloads + all waves' prev reads
        if (k0 + 32 < K) stage(buf ^ 1, k0 + 32);   // prefetch next tile

        bf16x8 af[4], bfr[4];
        #pragma unroll
        for (int mi = 0; mi < 4; mi++) {
            int row = wm * 64 + mi * 16 + lr;
            af[mi] = *(const bf16x8*)&As[buf][row * 32 + ((lg ^ ((row >> 1) & 3)) << 3)];
        }
        #pragma unroll
        for (int ni = 0; ni < 4; ni++) {
            int row = wn * 64 + ni * 16 + lr;
            bfr[ni] = *(const bf16x8*)&Bs[buf][row * 32 + ((lg ^ ((row >> 1) & 3)) << 3)];
        }
        #pragma unroll
        for (int mi = 0; mi < 4; mi++)
            #pragma unroll
            for (int ni = 0; ni < 4; ni++) {
                if constexpr (MODE == 3)
                    acc[mi][ni] = __builtin_amdgcn_mfma_f32_16x16x32_bf16(bfr[ni], af[mi], acc[mi][ni], 0, 0, 0);
                else
                    acc[mi][ni] = __builtin_amdgcn_mfma_f32_16x16x32_bf16(af[mi], bfr[ni], acc[mi][ni], 0, 0, 0);
            }
        buf ^= 1;
    }

    #pragma unroll
    for (int mi = 0; mi < 4; mi++)
        #pragma unroll
        for (int ni = 0; ni < 4; ni++) {
            f32x4 v4 = acc[mi][ni];
            #pragma unroll
            for (int r = 0; r < 4; r++) {
                float v = v4[r];
                if constexpr (MODE == 3) {
                    int n = n0 + wn * 64 + ni * 16 + lg * 4 + r;
                    int m = m0 + wm * 64 + mi * 16 + lr;
                    int h = n >> 6, d = n & 63;
                    int b = m >> 11, s = m & 2047;
                    ((u16*)Oo)[(((size_t)b * NH + h) * DK + d) * SEQ + s] = cbf(v);
                } else {
                    int m = m0 + wm * 64 + mi * 16 + lg * 4 + r;
                    int n = n0 + wn * 64 + ni * 16 + lr;
                    if constexpr (MODE == 2) {
                        ((float*)Oo)[(size_t)m * D_MODEL + n] = v;
                    } else {
                        int b = m >> 11, s = m & 2047;
                        int h = (n >> 6) & 15, d = n & 63;
                        float vp = __shfl_xor(v, 1);   // pair partner (n parity == lane parity)
                        int tp = tpos[s];
                        float2 c2 = cs[tp * 32 + (d >> 1)];
                        float res = (d & 1) ? (vp * c2.y + v * c2.x) : (v * c2.x - vp * c2.y);
                        const int sel = n0 >> 10;      // 0=Q (scaled), 1=K
                        if (sel == 0) res *= 0.18033688f;   // 0.125 * log2(e): softmax uses exp2
                        u16* outp = sel ? Ko : Qo;
                        outp[(((size_t)b * NH + h) * SEQ + s) * DK + d] = cbf(res);
                    }
                }
            }
        }
}

// ---------------- causal flash attention: persistent blocks + atomic work queue ----------------
// Q bf16 [b][h][s][dk] PRE-SCALED by 0.125*log2e; K bf16 [b][h][s][dk]; VT bf16 [b][h][dk][s].
// 1024 items = (qb, bh), decoded heavy-first: qb = 31-(item>>5), bh = item&31.
// Grid 1280 persistent blocks; each fetches items via device-scope atomicAdd (dynamic balance).
// Item published to the block through a mailbox in Vs[0] (LDS stays exactly 32 KB).
// Swapped softmax: S^T = mfma(K, Q); O^T = mfma(V^T, P^T); l via ones-fragment MFMA.
// K dbuf, V single-buf. Raw s_barrier + counted vmcnt inside the tile loop.
__global__ __launch_bounds__(256) void attn_kernel(
    const u16* __restrict__ Q,
    const u16* __restrict__ Km,
    const u16* __restrict__ VT,
    u16* __restrict__ aout,
    int* __restrict__ counter)
{
    __shared__ u16 Ks[2][64 * 64];   // [key][dk], 16B chunks XOR-swizzled by (key&7)
    __shared__ u16 Vs[64 * 64];      // [dk][key], 16B chunks XOR-swizzled by (dk&7); Vs[0..1] doubles as mailbox
    __shared__ u16 Pl[4][16 * 64];   // per-wave P [qrow][key], 8B chunks XOR-swizzled
    const int t = threadIdx.x, wid = t >> 6, lane = t & 63;
    const int lr = lane & 15, lg = lane >> 4;
    const int row0 = wid * 16;
    const int srow = lane >> 3, schunk = lane & 7;
    const int swz = (schunk ^ srow) << 3;
    u16* Plw = Pl[wid];
    volatile int* mailbox = (volatile int*)&Vs[0];

    bf16x8 onesf;
    #pragma unroll
    for (int e = 0; e < 8; e++) onesf[e] = (__bf16)1.0f;

    for (;;) {
        __syncthreads();   // all waves done reading prev item's LDS (incl. Vs); vmcnt drained
        if (t == 0) *mailbox = atomicAdd(counter, 1);
        __syncthreads();   // mailbox visible to all
        const int item = *mailbox;
        if (item >= 1024) return;                     // uniform across block

        const int qb = 31 - (item >> 5);              // heavy first
        const int bh = item & 31;
        const int b = bh >> 4, h = bh & 15;
        const int q0 = qb * 64;
        const int qw = q0 + row0;
        const int nkt = qb + 1;

        const u16* Qg = Q  + (size_t)bh * SEQ * DK;
        const u16* Kg = Km + (size_t)bh * SEQ * DK;
        const u16* Vg = VT + (size_t)bh * DK * SEQ;

        bf16x8 aq[2];
        #pragma unroll
        for (int h2 = 0; h2 < 2; h2++)
            aq[h2] = *(const bf16x8*)&Qg[(qw + lr) * DK + h2 * 32 + lg * 8];

        float m_run = -__builtin_inff();
        f32x4 acc[4];        // acc[dg]: O[qrow=qw+lr][d = dg*16+lg*4+r]
        f32x4 acc_l = 0.0f;  // ones-row MFMA: element 0 = running l[qrow=lr]
        #pragma unroll
        for (int dg = 0; dg < 4; dg++) acc[dg] = 0.0f;

        // running staging pointers (lane-fixed swizzled offsets, advance per tile)
        const u16* kptr = Kg + (size_t)(row0 + srow) * DK + swz;
        const u16* vptr = Vg + (size_t)(row0 + srow) * SEQ + swz;

        gload16(kptr,          &Ks[0][row0 * 64]);
        gload16(kptr + 8 * DK, &Ks[0][(row0 + 8) * 64]);
        kptr += 64 * DK;

        for (int kt = 0; kt < nkt; kt++) {
            __builtin_amdgcn_sched_barrier(0);
            __builtin_amdgcn_s_barrier();             // raw: no vmcnt drain
            __builtin_amdgcn_sched_barrier(0);
            // V[kt] (consumed late this iter); K[kt+1] (crosses next barrier in flight)
            gload16(vptr,                   &Vs[row0 * 64]);
            gload16(vptr + (size_t)8 * SEQ, &Vs[(row0 + 8) * 64]);
            vptr += 64;
            u16* kd = &Ks[(kt + 1) & 1][0];
            gload16(kptr,          kd + row0 * 64);
            gload16(kptr + 8 * DK, kd + (row0 + 8) * 64);
            kptr += 64 * DK;                          // last iter overruns into next region (in-ws, unread)
            const int kb = kt * 64;

            asm volatile("s_waitcnt vmcnt(4)" ::: "memory");   // K[kt] landed
            __builtin_amdgcn_sched_barrier(0);
            bf16x8 kf[4][2];
            #pragma unroll
            for (int kg = 0; kg < 4; kg++)
                #pragma unroll
                for (int h2 = 0; h2 < 2; h2++) {
                    int row = kg * 16 + lr;
                    kf[kg][h2] = *(const bf16x8*)&Ks[kt & 1][row * 64 + (((h2 * 4 + lg) ^ (lr & 7)) << 3)];
                }

            // S^T[key][qrow] = K . Q^T  (lane: qrow = lr, key = kg*16+lg*4+r)
            f32x4 sf[4];
            #pragma unroll
            for (int kg = 0; kg < 4; kg++) sf[kg] = 0.0f;
            __builtin_amdgcn_s_setprio(1);
            #pragma unroll
            for (int kg = 0; kg < 4; kg++) {
                sf[kg] = __builtin_amdgcn_mfma_f32_16x16x32_bf16(kf[kg][0], aq[0], sf[kg], 0, 0, 0);
                sf[kg] = __builtin_amdgcn_mfma_f32_16x16x32_bf16(kf[kg][1], aq[1], sf[kg], 0, 0, 0);
            }
            __builtin_amdgcn_s_setprio(0);

            {
                if (kb + 64 > qw) {                   // diagonal band (last tile per wave): mask
                    const int qq = qw + lr;
                    #pragma unroll
                    for (int kg = 0; kg < 4; kg++)
                        #pragma unroll
                        for (int r = 0; r < 4; r++)
                            if (kb + kg * 16 + lg * 4 + r > qq) sf[kg][r] = -__builtin_inff();
                }
                // tree max (depth 4, max3-fusable)
                float mk[4];
                #pragma unroll
                for (int kg = 0; kg < 4; kg++)
                    mk[kg] = fmaxf(fmaxf(sf[kg][0], sf[kg][1]), fmaxf(sf[kg][2], sf[kg][3]));
                float cmax = fmaxf(fmaxf(mk[0], mk[1]), fmaxf(mk[2], mk[3]));
                if (!__all(cmax <= m_run + 8.0f)) {   // defer-max (log2 units)
                    float mt = fmaxf(cmax, __shfl_xor(cmax, 16));
                    mt = fmaxf(mt, __shfl_xor(mt, 32));
                    float mn = fmaxf(m_run, mt);
                    float scr = exp2f(m_run - mn);
                    m_run = mn;
                    acc_l[0] *= scr;                  // only element 0 is read at the end
                    #pragma unroll
                    for (int dg = 0; dg < 4; dg++) acc[dg] *= scr;
                }
                const int prow = lr * 64;
                #pragma unroll
                for (int kg = 0; kg < 4; kg++) {
                    ushx4 pk;
                    #pragma unroll
                    for (int r = 0; r < 4; r++)
                        pk[r] = cbf(exp2f(sf[kg][r] - m_run));
                    *(ushx4*)&Plw[prow + (((kg * 4 + lg) ^ ((lr & 7) << 1)) << 2)] = pk;
                }
            }

            asm volatile("s_waitcnt vmcnt(2)" ::: "memory");   // V[kt] landed (K[kt+1] flies)
            __builtin_amdgcn_sched_barrier(0);
            bf16x8 vf[2][4];
            #pragma unroll
            for (int ck = 0; ck < 2; ck++)
                #pragma unroll
                for (int dg = 0; dg < 4; dg++) {
                    int row = dg * 16 + lr;
                    vf[ck][dg] = *(const bf16x8*)&Vs[row * 64 + (((ck * 4 + lg) ^ (lr & 7)) << 3)];
                }

            asm volatile("s_waitcnt lgkmcnt(0)" ::: "memory");   // P writes done (same-wave DS order)
            __builtin_amdgcn_sched_barrier(0);
            bf16x8 pa[2];
            #pragma unroll
            for (int ck = 0; ck < 2; ck++)
                pa[ck] = *(const bf16x8*)&Plw[lr * 64 + (((ck * 8 + lg * 2) ^ ((lr & 7) << 1)) << 2)];
            __builtin_amdgcn_s_setprio(1);
            #pragma unroll
            for (int ck = 0; ck < 2; ck++) {
                #pragma unroll
                for (int dg = 0; dg < 4; dg++)
                    acc[dg] = __builtin_amdgcn_mfma_f32_16x16x32_bf16(vf[ck][dg], pa[ck], acc[dg], 0, 0, 0);
                acc_l = __builtin_amdgcn_mfma_f32_16x16x32_bf16(onesf, pa[ck], acc_l, 0, 0, 0);
            }
            __builtin_amdgcn_s_setprio(0);
        }

        {
            float inv = 1.0f / acc_l[0];              // l[qrow=lr], no cross-lane reduce needed
            int q = qw + lr;
            #pragma unroll
            for (int dg = 0; dg < 4; dg++) {
                ushx4 ow;
                #pragma unroll
                for (int r = 0; r < 4; r++) ow[r] = cbf(acc[dg][r] * inv);
                *(ushx4*)&aout[((size_t)b * SEQ + q) * D_MODEL + h * DK + dg * 16 + lg * 4] = ow;
            }
        }
    }
}

extern "C" void kernel_launch(void* const* d_in, const int* in_sizes, int n_in,
                              void* d_out, int out_size, void* d_ws, size_t ws_size,
                              hipStream_t stream) {
    const float* x    = (const float*)d_in[0];
    const int*   tpos = (const int*)d_in[1];
    const float* Wq   = (const float*)d_in[2];
    const float* Wk   = (const float*)d_in[3];
    const float* Wv   = (const float*)d_in[4];
    const float* Wo   = (const float*)d_in[5];
    float* out = (float*)d_out;
    int* counter = (int*)d_out;   // dead until gemm_bt<2> overwrites; rope zeroes it each call

    char* ws = (char*)d_ws;
    float2* cs = (float2*)ws;                                   // 512 KB
    u16* Qb   = (u16*)(ws + (512 << 10));                       // 8 MB
    u16* Kb   = (u16*)(ws + (512 << 10) + ((size_t)8  << 20));  // 8 MB
    u16* VT   = (u16*)(ws + (512 << 10) + ((size_t)16 << 20));  // 8 MB
    u16* xb   = (u16*)(ws + (512 << 10) + ((size_t)24 << 20));  // 8 MB (reused as attnb)
    u16* Wqb  = (u16*)(ws + (512 << 10) + ((size_t)32 << 20));  // 2 MB -- Wq/Wk contiguous
    u16* Wkb  = (u16*)(ws + (512 << 10) + ((size_t)34 << 20));
    u16* Wvb  = (u16*)(ws + (512 << 10) + ((size_t)36 << 20));
    u16* Wob  = (u16*)(ws + (512 << 10) + ((size_t)38 << 20));  // total 40.5 MB
    u16* attnb = xb;   // x no longer needed once QKV GEMMs are done (stream-ordered)

    rope_tables_kernel<<<256, 256, 0, stream>>>(cs, counter);
    cvt_kernel<<<2048, 256, 0, stream>>>(x, xb);
    cvtw_kernel<<<dim3(512, 4), 256, 0, stream>>>(Wq, Wk, Wv, Wo, Wqb, Wkb, Wvb, Wob);

    gemm_bt<0><<<dim3(32, 16), 256, 0, stream>>>(xb, Wqb, Qb, Kb, nullptr, tpos, cs);
    gemm_bt<3><<<dim3(32, 8),  256, 0, stream>>>(xb, Wvb, nullptr, nullptr, VT, tpos, cs);

    attn_kernel<<<1280, 256, 0, stream>>>(Qb, Kb, VT, attnb, counter);

    gemm_bt<2><<<dim3(32, 8),  256, 0, stream>>>(attnb, Wob, nullptr, nullptr, out, tpos, cs);
}

// Round 14
// 138.398 us; speedup vs baseline: 1.0637x; 1.0637x over previous
//
#include <hip/hip_runtime.h>
#include <hip/hip_bf16.h>
#include <math.h>

#define D_MODEL 1024
#define NH      16
#define DK      64
#define SEQ     2048
#define BATCH   2

typedef float  f32x4  __attribute__((ext_vector_type(4)));
typedef __bf16 bf16x8 __attribute__((ext_vector_type(8)));
typedef unsigned short ushx4 __attribute__((ext_vector_type(4)));
typedef unsigned short ushx8 __attribute__((ext_vector_type(8)));
typedef unsigned short u16;

// RNE float->bf16 via compiler cast (single v_cvt on gfx950)
__device__ inline u16 cbf(float f) { __bf16 h = (__bf16)f; return *(u16*)&h; }

__device__ inline void gload16(const u16* g, u16* l) {
    // direct global->LDS DMA, 16B/lane, dest = wave-uniform base + lane*16
    __builtin_amdgcn_global_load_lds(
        (const __attribute__((address_space(1))) unsigned int*)g,
        (__attribute__((address_space(3))) unsigned int*)l,
        16, 0, 0);
}

// ---------------- RoPE tables: interleaved (cos,sin) [SEQ][DK/2] ----------------
__global__ void rope_tables_kernel(float2* __restrict__ cs) {
    int i = blockIdx.x * 256 + threadIdx.x;      // 2048*32 = 65536 total
    int pos = i >> 5, k = i & 31;
    float inv = powf(10000.0f, -2.0f * (float)k / 64.0f);
    float ang = (float)pos * inv;
    cs[i] = make_float2(cosf(ang), sinf(ang));
}

// ---------------- fp32 -> bf16 converts ----------------
__global__ void cvt_kernel(const float* __restrict__ in, u16* __restrict__ out) {
    size_t i = ((size_t)blockIdx.x * 256 + threadIdx.x) * 8;
    f32x4 v0 = *(const f32x4*)(in + i);
    f32x4 v1 = *(const f32x4*)(in + i + 4);
    ushx4 o0, o1;
    #pragma unroll
    for (int e = 0; e < 4; e++) { o0[e] = cbf(v0[e]); o1[e] = cbf(v1[e]); }
    *(ushx4*)(out + i) = o0;
    *(ushx4*)(out + i + 4) = o1;
}

__global__ void cvtw_kernel(const float* __restrict__ wq, const float* __restrict__ wk,
                            const float* __restrict__ wv, const float* __restrict__ wo,
                            u16* __restrict__ oq, u16* __restrict__ ok,
                            u16* __restrict__ ov, u16* __restrict__ oo) {
    const float* in; u16* out;
    switch (blockIdx.y) {
        case 0: in = wq; out = oq; break;
        case 1: in = wk; out = ok; break;
        case 2: in = wv; out = ov; break;
        default: in = wo; out = oo; break;
    }
    size_t i = ((size_t)blockIdx.x * 256 + threadIdx.x) * 8;
    f32x4 v0 = *(const f32x4*)(in + i);
    f32x4 v1 = *(const f32x4*)(in + i + 4);
    ushx4 o0, o1;
    #pragma unroll
    for (int e = 0; e < 4; e++) { o0[e] = cbf(v0[e]); o1[e] = cbf(v1[e]); }
    *(ushx4*)(out + i) = o0;
    *(ushx4*)(out + i + 4) = o1;
}

// ---------------- GEMM C[m][n] = sum_k A[m][k] W[n][k], BM=64 BN=128, 2-phase dbuf ----------------
// Tile 64x128, 4 waves (2x2, each 32x64), LDS 24 KB -> 4 blocks/CU possible.
// MODE 0: n in [0,2048): RoPE epilogue -> Qo (pre-scaled 0.125*log2e) / Ko, bf16 [b][h][s][dk]
// MODE 2: fp32 out [m][n]
// MODE 3: swapped operands (rows=n, cols=m) -> coalesced V^T store, bf16 [b][h][dk][s]
template<int MODE>
__global__ __launch_bounds__(256) void gemm_bt(
    const u16* __restrict__ A, const u16* __restrict__ W,
    u16* __restrict__ Qo, u16* __restrict__ Ko, void* __restrict__ Oo,
    const int* __restrict__ tpos, const float2* __restrict__ cs)
{
    constexpr int K = 1024;
    __shared__ u16 As[2][64 * 32];
    __shared__ u16 Bs[2][128 * 32];

    const int t  = threadIdx.x;
    const int m0 = blockIdx.x * 64, n0 = blockIdx.y * 128;
    const int lane = t & 63, wid = t >> 6;
    const int wm = wid >> 1, wn = wid & 1;       // 2x2 wave grid, 32x64 per wave
    const int lr = lane & 15, lg = lane >> 4;
    const int lc = lane & 3;

    // A staging: 1 gload/wave (16 rows); B staging: 2 gloads/wave (32 rows).
    // LDS linear; source chunk pre-swizzled by (row>>1)&3 (rule 21; proven r5-r13).
    const int arow = wid * 16 + (lane >> 2);
    const int brow0 = wid * 32 + (lane >> 2);
    const int brow1 = brow0 + 16;
    const u16* Asrc  = A + (size_t)(m0 + arow) * K + ((lc ^ ((arow >> 1) & 3)) << 3);
    const u16* Bsrc0 = W + (size_t)(n0 + brow0) * K + ((lc ^ ((brow0 >> 1) & 3)) << 3);
    const u16* Bsrc1 = W + (size_t)(n0 + brow1) * K + ((lc ^ ((brow1 >> 1) & 3)) << 3);
    const int da = (wid * 16) * 32, db0 = (wid * 32) * 32, db1 = (wid * 32 + 16) * 32;

    f32x4 acc[2][4];
    #pragma unroll
    for (int i = 0; i < 2; i++)
        #pragma unroll
        for (int j2 = 0; j2 < 4; j2++) acc[i][j2] = 0.0f;

    auto stage = [&](int buf, int k0) {
        gload16(Asrc  + k0, &As[buf][da]);
        gload16(Bsrc0 + k0, &Bs[buf][db0]);
        gload16(Bsrc1 + k0, &Bs[buf][db1]);
    };

    stage(0, 0);
    int buf = 0;
    for (int k0 = 0; k0 < K; k0 += 32) {
        __syncthreads();                 // drains my stage gloads + all waves' prev reads
        if (k0 + 32 < K) stage(buf ^ 1, k0 + 32);   // prefetch next tile

        bf16x8 af[2], bfr[4];
        #pragma unroll
        for (int mi = 0; mi < 2; mi++) {
            int row = wm * 32 + mi * 16 + lr;
            af[mi] = *(const bf16x8*)&As[buf][row * 32 + ((lg ^ ((row >> 1) & 3)) << 3)];
        }
        #pragma unroll
        for (int ni = 0; ni < 4; ni++) {
            int row = wn * 64 + ni * 16 + lr;
            bfr[ni] = *(const bf16x8*)&Bs[buf][row * 32 + ((lg ^ ((row >> 1) & 3)) << 3)];
        }
        #pragma unroll
        for (int mi = 0; mi < 2; mi++)
            #pragma unroll
            for (int ni = 0; ni < 4; ni++) {
                if constexpr (MODE == 3)
                    acc[mi][ni] = __builtin_amdgcn_mfma_f32_16x16x32_bf16(bfr[ni], af[mi], acc[mi][ni], 0, 0, 0);
                else
                    acc[mi][ni] = __builtin_amdgcn_mfma_f32_16x16x32_bf16(af[mi], bfr[ni], acc[mi][ni], 0, 0, 0);
            }
        buf ^= 1;
    }

    #pragma unroll
    for (int mi = 0; mi < 2; mi++)
        #pragma unroll
        for (int ni = 0; ni < 4; ni++) {
            f32x4 v4 = acc[mi][ni];
            #pragma unroll
            for (int r = 0; r < 4; r++) {
                float v = v4[r];
                if constexpr (MODE == 3) {
                    int n = n0 + wn * 64 + ni * 16 + lg * 4 + r;
                    int m = m0 + wm * 32 + mi * 16 + lr;
                    int h = n >> 6, d = n & 63;
                    int b = m >> 11, s = m & 2047;
                    ((u16*)Oo)[(((size_t)b * NH + h) * DK + d) * SEQ + s] = cbf(v);
                } else {
                    int m = m0 + wm * 32 + mi * 16 + lg * 4 + r;
                    int n = n0 + wn * 64 + ni * 16 + lr;
                    if constexpr (MODE == 2) {
                        ((float*)Oo)[(size_t)m * D_MODEL + n] = v;
                    } else {
                        int b = m >> 11, s = m & 2047;
                        int h = (n >> 6) & 15, d = n & 63;
                        float vp = __shfl_xor(v, 1);   // pair partner (n parity == lane parity)
                        int tp = tpos[s];
                        float2 c2 = cs[tp * 32 + (d >> 1)];
                        float res = (d & 1) ? (vp * c2.y + v * c2.x) : (v * c2.x - vp * c2.y);
                        const int sel = n0 >> 10;      // 0=Q (scaled), 1=K
                        if (sel == 0) res *= 0.18033688f;   // 0.125 * log2(e): softmax uses exp2
                        u16* outp = sel ? Ko : Qo;
                        outp[(((size_t)b * NH + h) * SEQ + s) * DK + d] = cbf(res);
                    }
                }
            }
        }
}

// ---------------- causal flash attention, QBLK=64, grid 1024 (round-9 verbatim: 51 us) ----------------
// Q bf16 [b][h][s][dk] PRE-SCALED by 0.125*log2e; K bf16 [b][h][s][dk]; VT bf16 [b][h][dk][s].
// Block = 64 q-rows of one (b,h); wave w owns rows qw..qw+15. Grid 1024 = 32 qb x 32 bh.
// qb = 31-(bx>>5) descending (heavy first); bh = (bx&7)*4 + ((bx>>3)&3) -> 4 heads/XCD (L2-resident).
// Swapped softmax: S^T = mfma(K, Q); O^T = mfma(V^T, P^T).
// K dbuf, V single-buf (32 KB LDS). Raw s_barrier + counted vmcnt.
__global__ __launch_bounds__(256) void attn_kernel(
    const u16* __restrict__ Q,
    const u16* __restrict__ Km,
    const u16* __restrict__ VT,
    u16* __restrict__ aout)
{
    __shared__ u16 Ks[2][64 * 64];   // [key][dk], 16B chunks XOR-swizzled by (key&7)
    __shared__ u16 Vs[64 * 64];      // [dk][key], 16B chunks XOR-swizzled by (dk&7)
    __shared__ u16 Pl[4][16 * 64];   // per-wave P [qrow][key], 8B chunks XOR-swizzled
    const int t = threadIdx.x, wid = t >> 6, lane = t & 63;
    const int lr = lane & 15, lg = lane >> 4;
    const int bx = blockIdx.x;
    const int j = bx & 31;
    const int qb = 31 - (bx >> 5);                    // descending work: tail = tiny blocks
    const int bh = (j & 7) * 4 + (j >> 3);            // 4 heads per XCD
    const int b = bh >> 4, h = bh & 15;
    const int q0 = qb * 64;
    const int row0 = wid * 16;
    const int qw = q0 + row0;
    const int nkt = qb + 1;
    const int srow = lane >> 3, schunk = lane & 7;
    const int swz = (schunk ^ srow) << 3;

    const u16* Qg = Q  + (size_t)bh * SEQ * DK;
    const u16* Kg = Km + (size_t)bh * SEQ * DK;
    const u16* Vg = VT + (size_t)bh * DK * SEQ;
    u16* Plw = Pl[wid];

    bf16x8 aq[2];
    #pragma unroll
    for (int h2 = 0; h2 < 2; h2++)
        aq[h2] = *(const bf16x8*)&Qg[(qw + lr) * DK + h2 * 32 + lg * 8];

    float m_run = -__builtin_inff(), l_run = 0.0f;
    f32x4 acc[4];   // acc[dg]: O[qrow=qw+lr][d = dg*16+lg*4+r]
    #pragma unroll
    for (int dg = 0; dg < 4; dg++) acc[dg] = 0.0f;

    auto stageK = [&](int buf, int kb) {              // 2 gloads per wave
        const u16* ks = Kg + (size_t)(kb + row0 + srow) * DK + swz;
        gload16(ks,          &Ks[buf][row0 * 64]);
        gload16(ks + 8 * DK, &Ks[buf][(row0 + 8) * 64]);
    };
    auto stageV = [&](int kb) {                       // 2 gloads per wave
        const u16* vs = Vg + (size_t)(row0 + srow) * SEQ + kb + swz;
        gload16(vs,                   &Vs[row0 * 64]);
        gload16(vs + (size_t)8 * SEQ, &Vs[(row0 + 8) * 64]);
    };

    stageK(0, 0);
    for (int kt = 0; kt < nkt; kt++) {
        __builtin_amdgcn_sched_barrier(0);
        __builtin_amdgcn_s_barrier();                 // raw: no vmcnt drain
        __builtin_amdgcn_sched_barrier(0);
        stageV(kt * 64);                              // V[kt] (consumed late this iter)
        stageK((kt + 1) & 1, (kt + 1 < nkt) ? (kt + 1) * 64 : 0);  // K[kt+1] (redundant on last)
        const int kb = kt * 64;

        asm volatile("s_waitcnt vmcnt(4)" ::: "memory");   // K[kt] landed (V[kt],K[kt+1] fly)
        __builtin_amdgcn_sched_barrier(0);
        bf16x8 kf[4][2];
        #pragma unroll
        for (int kg = 0; kg < 4; kg++)
            #pragma unroll
            for (int h2 = 0; h2 < 2; h2++) {
                int row = kg * 16 + lr;
                kf[kg][h2] = *(const bf16x8*)&Ks[kt & 1][row * 64 + (((h2 * 4 + lg) ^ (lr & 7)) << 3)];
            }

        f32x4 sf[4];
        #pragma unroll
        for (int kg = 0; kg < 4; kg++) sf[kg] = 0.0f;
        __builtin_amdgcn_s_setprio(1);
        #pragma unroll
        for (int kg = 0; kg < 4; kg++) {
            sf[kg] = __builtin_amdgcn_mfma_f32_16x16x32_bf16(kf[kg][0], aq[0], sf[kg], 0, 0, 0);
            sf[kg] = __builtin_amdgcn_mfma_f32_16x16x32_bf16(kf[kg][1], aq[1], sf[kg], 0, 0, 0);
        }
        __builtin_amdgcn_s_setprio(0);

        {
            if (kb + 64 > qw) {                       // diagonal band: mask
                const int qq = qw + lr;
                #pragma unroll
                for (int kg = 0; kg < 4; kg++)
                    #pragma unroll
                    for (int r = 0; r < 4; r++)
                        if (kb + kg * 16 + lg * 4 + r > qq) sf[kg][r] = -__builtin_inff();
            }
            float cmax = sf[0][0];
            #pragma unroll
            for (int kg = 0; kg < 4; kg++)
                #pragma unroll
                for (int r = 0; r < 4; r++) cmax = fmaxf(cmax, sf[kg][r]);
            if (!__all(cmax <= m_run + 8.0f)) {       // defer-max (log2 units)
                float mt = fmaxf(cmax, __shfl_xor(cmax, 16));
                mt = fmaxf(mt, __shfl_xor(mt, 32));
                float mn = fmaxf(m_run, mt);
                float scr = exp2f(m_run - mn);
                m_run = mn;
                l_run *= scr;
                #pragma unroll
                for (int dg = 0; dg < 4; dg++) acc[dg] *= scr;
            }
            float l = 0.0f;
            const int prow = lr * 64;
            #pragma unroll
            for (int kg = 0; kg < 4; kg++) {
                ushx4 pk;
                #pragma unroll
                for (int r = 0; r < 4; r++) {
                    float pv = exp2f(sf[kg][r] - m_run);
                    l += pv;
                    pk[r] = cbf(pv);
                }
                *(ushx4*)&Plw[prow + (((kg * 4 + lg) ^ ((lr & 7) << 1)) << 2)] = pk;
            }
            l_run += l;                               // per-lane partial (this lane's 16 keys)
        }

        asm volatile("s_waitcnt vmcnt(2)" ::: "memory");   // V[kt] landed (K[kt+1] flies)
        __builtin_amdgcn_sched_barrier(0);
        bf16x8 vf[2][4];
        #pragma unroll
        for (int ck = 0; ck < 2; ck++)
            #pragma unroll
            for (int dg = 0; dg < 4; dg++) {
                int row = dg * 16 + lr;
                vf[ck][dg] = *(const bf16x8*)&Vs[row * 64 + (((ck * 4 + lg) ^ (lr & 7)) << 3)];
            }

        asm volatile("s_waitcnt lgkmcnt(0)" ::: "memory");   // P writes done (same-wave DS order)
        __builtin_amdgcn_sched_barrier(0);
        bf16x8 pa[2];
        #pragma unroll
        for (int ck = 0; ck < 2; ck++)
            pa[ck] = *(const bf16x8*)&Plw[lr * 64 + (((ck * 8 + lg * 2) ^ ((lr & 7) << 1)) << 2)];
        __builtin_amdgcn_s_setprio(1);
        #pragma unroll
        for (int ck = 0; ck < 2; ck++)
            #pragma unroll
            for (int dg = 0; dg < 4; dg++)
                acc[dg] = __builtin_amdgcn_mfma_f32_16x16x32_bf16(vf[ck][dg], pa[ck], acc[dg], 0, 0, 0);
        __builtin_amdgcn_s_setprio(0);
    }

    l_run += __shfl_xor(l_run, 16);
    l_run += __shfl_xor(l_run, 32);

    {
        float inv = 1.0f / l_run;
        int q = qw + lr;
        #pragma unroll
        for (int dg = 0; dg < 4; dg++) {
            ushx4 ow;
            #pragma unroll
            for (int r = 0; r < 4; r++) ow[r] = cbf(acc[dg][r] * inv);
            *(ushx4*)&aout[((size_t)b * SEQ + q) * D_MODEL + h * DK + dg * 16 + lg * 4] = ow;
        }
    }
}

extern "C" void kernel_launch(void* const* d_in, const int* in_sizes, int n_in,
                              void* d_out, int out_size, void* d_ws, size_t ws_size,
                              hipStream_t stream) {
    const float* x    = (const float*)d_in[0];
    const int*   tpos = (const int*)d_in[1];
    const float* Wq   = (const float*)d_in[2];
    const float* Wk   = (const float*)d_in[3];
    const float* Wv   = (const float*)d_in[4];
    const float* Wo   = (const float*)d_in[5];
    float* out = (float*)d_out;

    char* ws = (char*)d_ws;
    float2* cs = (float2*)ws;                                   // 512 KB
    u16* Qb   = (u16*)(ws + (512 << 10));                       // 8 MB
    u16* Kb   = (u16*)(ws + (512 << 10) + ((size_t)8  << 20));  // 8 MB
    u16* VT   = (u16*)(ws + (512 << 10) + ((size_t)16 << 20));  // 8 MB
    u16* xb   = (u16*)(ws + (512 << 10) + ((size_t)24 << 20));  // 8 MB (reused as attnb)
    u16* Wqb  = (u16*)(ws + (512 << 10) + ((size_t)32 << 20));  // 2 MB -- Wq/Wk contiguous
    u16* Wkb  = (u16*)(ws + (512 << 10) + ((size_t)34 << 20));
    u16* Wvb  = (u16*)(ws + (512 << 10) + ((size_t)36 << 20));
    u16* Wob  = (u16*)(ws + (512 << 10) + ((size_t)38 << 20));  // total 40.5 MB
    u16* attnb = xb;   // x no longer needed once QKV GEMMs are done (stream-ordered)

    rope_tables_kernel<<<256, 256, 0, stream>>>(cs);
    cvt_kernel<<<2048, 256, 0, stream>>>(x, xb);
    cvtw_kernel<<<dim3(512, 4), 256, 0, stream>>>(Wq, Wk, Wv, Wo, Wqb, Wkb, Wvb, Wob);

    gemm_bt<0><<<dim3(64, 16), 256, 0, stream>>>(xb, Wqb, Qb, Kb, nullptr, tpos, cs);
    gemm_bt<3><<<dim3(64, 8),  256, 0, stream>>>(xb, Wvb, nullptr, nullptr, VT, tpos, cs);

    attn_kernel<<<1024, 256, 0, stream>>>(Qb, Kb, VT, attnb);

    gemm_bt<2><<<dim3(64, 8),  256, 0, stream>>>(attnb, Wob, nullptr, nullptr, out, tpos, cs);
}

// Round 15
// 123.702 us; speedup vs baseline: 1.1901x; 1.1188x over previous
//
#include <hip/hip_runtime.h>
#include <hip/hip_bf16.h>
#include <math.h>

#define D_MODEL 1024
#define NH      16
#define DK      64
#define SEQ     2048
#define BATCH   2

typedef float  f32x4  __attribute__((ext_vector_type(4)));
typedef __bf16 bf16x8 __attribute__((ext_vector_type(8)));
typedef unsigned short ushx4 __attribute__((ext_vector_type(4)));
typedef unsigned short ushx8 __attribute__((ext_vector_type(8)));
typedef unsigned short u16;

// RNE float->bf16 via compiler cast (single v_cvt on gfx950)
__device__ inline u16 cbf(float f) { __bf16 h = (__bf16)f; return *(u16*)&h; }

__device__ inline void gload16(const u16* g, u16* l) {
    // direct global->LDS DMA, 16B/lane, dest = wave-uniform base + lane*16
    __builtin_amdgcn_global_load_lds(
        (const __attribute__((address_space(1))) unsigned int*)g,
        (__attribute__((address_space(3))) unsigned int*)l,
        16, 0, 0);
}

// ---------------- fused prep: x/W fp32->bf16 + RoPE tables (1 launch) ----------------
__global__ void prep_kernel(const float* __restrict__ x,
                            const float* __restrict__ wq, const float* __restrict__ wk,
                            const float* __restrict__ wv, const float* __restrict__ wo,
                            u16* __restrict__ xb,
                            u16* __restrict__ wqb, u16* __restrict__ wkb,
                            u16* __restrict__ wvb, u16* __restrict__ wob,
                            float2* __restrict__ cs)
{
    const int bx = blockIdx.x, t = threadIdx.x;
    if (bx < 4096) {
        const float* in; u16* out; size_t base;
        if (bx < 2048) { in = x; out = xb; base = (size_t)bx * 2048; }
        else {
            int i = bx - 2048, sel = i >> 9;
            base = (size_t)(i & 511) * 2048;
            switch (sel) {
                case 0:  in = wq; out = wqb; break;
                case 1:  in = wk; out = wkb; break;
                case 2:  in = wv; out = wvb; break;
                default: in = wo; out = wob; break;
            }
        }
        size_t idx = base + (size_t)t * 8;
        f32x4 v0 = *(const f32x4*)(in + idx);
        f32x4 v1 = *(const f32x4*)(in + idx + 4);
        ushx4 o0, o1;
        #pragma unroll
        for (int e = 0; e < 4; e++) { o0[e] = cbf(v0[e]); o1[e] = cbf(v1[e]); }
        *(ushx4*)(out + idx) = o0;
        *(ushx4*)(out + idx + 4) = o1;
    } else {
        int i = (bx - 4096) * 256 + t;              // 2048*32 = 65536 total
        int pos = i >> 5, k = i & 31;
        float inv = powf(10000.0f, -2.0f * (float)k / 64.0f);
        float ang = (float)pos * inv;
        cs[i] = make_float2(cosf(ang), sinf(ang));
    }
}

// ---------------- GEMM C[m][n] = sum_k A[m][k] W[n][k], 2-phase dbuf (r9-proven) ----------------
// MODE 0: n in [0,2048): RoPE epilogue -> Qo (pre-scaled 0.125*log2e) / Ko, bf16 [b][h][s][dk]
// MODE 2: fp32 out [m][n]
// MODE 3: swapped operands (rows=n, cols=m) -> coalesced V^T store, bf16 [b][h][dk][s]
template<int MODE>
__global__ __launch_bounds__(256) void gemm_bt(
    const u16* __restrict__ A, const u16* __restrict__ W,
    u16* __restrict__ Qo, u16* __restrict__ Ko, void* __restrict__ Oo,
    const int* __restrict__ tpos, const float2* __restrict__ cs)
{
    constexpr int K = 1024;
    __shared__ u16 As[2][128 * 32];
    __shared__ u16 Bs[2][128 * 32];

    const int t  = threadIdx.x;
    const int m0 = blockIdx.x * 128, n0 = blockIdx.y * 128;
    const int lane = t & 63, wid = t >> 6;
    const int wm = wid >> 1, wn = wid & 1;       // 2x2 wave grid, 64x64 per wave
    const int lr = lane & 15, lg = lane >> 4;

    const int ldrow0 = wid * 32 + (lane >> 2);
    const int ldrow1 = ldrow0 + 16;
    const int lc = lane & 3;
    const u16* Asrc0 = A + (size_t)(m0 + ldrow0) * K + ((lc ^ ((ldrow0 >> 1) & 3)) << 3);
    const u16* Asrc1 = A + (size_t)(m0 + ldrow1) * K + ((lc ^ ((ldrow1 >> 1) & 3)) << 3);
    const u16* Bsrc0 = W + (size_t)(n0 + ldrow0) * K + ((lc ^ ((ldrow0 >> 1) & 3)) << 3);
    const u16* Bsrc1 = W + (size_t)(n0 + ldrow1) * K + ((lc ^ ((ldrow1 >> 1) & 3)) << 3);
    const int d0 = (wid * 32) * 32, d1 = (wid * 32 + 16) * 32;

    f32x4 acc[4][4];
    #pragma unroll
    for (int i = 0; i < 4; i++)
        #pragma unroll
        for (int j2 = 0; j2 < 4; j2++) acc[i][j2] = 0.0f;

    auto stage = [&](int buf, int k0) {
        gload16(Asrc0 + k0, &As[buf][d0]);
        gload16(Asrc1 + k0, &As[buf][d1]);
        gload16(Bsrc0 + k0, &Bs[buf][d0]);
        gload16(Bsrc1 + k0, &Bs[buf][d1]);
    };

    stage(0, 0);
    int buf = 0;
    for (int k0 = 0; k0 < K; k0 += 32) {
        __syncthreads();                 // drains my stage gloads + all waves' prev reads
        if (k0 + 32 < K) stage(buf ^ 1, k0 + 32);   // prefetch next tile

        bf16x8 af[4], bfr[4];
        #pragma unroll
        for (int mi = 0; mi < 4; mi++) {
            int row = wm * 64 + mi * 16 + lr;
            af[mi] = *(const bf16x8*)&As[buf][row * 32 + ((lg ^ ((row >> 1) & 3)) << 3)];
        }
        #pragma unroll
        for (int ni = 0; ni < 4; ni++) {
            int row = wn * 64 + ni * 16 + lr;
            bfr[ni] = *(const bf16x8*)&Bs[buf][row * 32 + ((lg ^ ((row >> 1) & 3)) << 3)];
        }
        #pragma unroll
        for (int mi = 0; mi < 4; mi++)
            #pragma unroll
            for (int ni = 0; ni < 4; ni++) {
                if constexpr (MODE == 3)
                    acc[mi][ni] = __builtin_amdgcn_mfma_f32_16x16x32_bf16(bfr[ni], af[mi], acc[mi][ni], 0, 0, 0);
                else
                    acc[mi][ni] = __builtin_amdgcn_mfma_f32_16x16x32_bf16(af[mi], bfr[ni], acc[mi][ni], 0, 0, 0);
            }
        buf ^= 1;
    }

    #pragma unroll
    for (int mi = 0; mi < 4; mi++)
        #pragma unroll
        for (int ni = 0; ni < 4; ni++) {
            f32x4 v4 = acc[mi][ni];
            #pragma unroll
            for (int r = 0; r < 4; r++) {
                float v = v4[r];
                if constexpr (MODE == 3) {
                    int n = n0 + wn * 64 + ni * 16 + lg * 4 + r;
                    int m = m0 + wm * 64 + mi * 16 + lr;
                    int h = n >> 6, d = n & 63;
                    int b = m >> 11, s = m & 2047;
                    ((u16*)Oo)[(((size_t)b * NH + h) * DK + d) * SEQ + s] = cbf(v);
                } else {
                    int m = m0 + wm * 64 + mi * 16 + lg * 4 + r;
                    int n = n0 + wn * 64 + ni * 16 + lr;
                    if constexpr (MODE == 2) {
                        ((float*)Oo)[(size_t)m * D_MODEL + n] = v;
                    } else {
                        int b = m >> 11, s = m & 2047;
                        int h = (n >> 6) & 15, d = n & 63;
                        float vp = __shfl_xor(v, 1);   // pair partner (n parity == lane parity)
                        int tp = tpos[s];
                        float2 c2 = cs[tp * 32 + (d >> 1)];
                        float res = (d & 1) ? (vp * c2.y + v * c2.x) : (v * c2.x - vp * c2.y);
                        const int sel = n0 >> 10;      // 0=Q (scaled), 1=K
                        if (sel == 0) res *= 0.18033688f;   // 0.125 * log2(e): softmax uses exp2
                        u16* outp = sel ? Ko : Qo;
                        outp[(((size_t)b * NH + h) * SEQ + s) * DK + d] = cbf(res);
                    }
                }
            }
        }
}

// ---------------- causal flash attention, QBLK=64, PV pipelined one tile back ----------------
// Q bf16 [b][h][s][dk] PRE-SCALED by 0.125*log2e; K bf16 [b][h][s][dk]; VT bf16 [b][h][dk][s].
// Block = 64 q-rows of one (b,h); wave w owns rows qw..qw+15. Grid 1024 = 32 qb x 32 bh.
// qb = 31-(bx>>5) descending; bh = (bx&7)*4 + ((bx>>3)&3) -> 4 heads/XCD (L2-resident).
// Swapped softmax: S^T = mfma(K, Q); O^T = mfma(V^T, P^T).
// K dbuf + V dbuf (40 KB LDS, 4 blocks/CU). Body kt: QK[kt] then PV[kt-1] (paR regs +
// Vs[(kt-1)&1]) then SM[kt] -> PV leaves the serial chain; SM VALU overlaps PV MFMA.
// One vmcnt(4)/tile (FIFO: draining K[kt] also drains V[kt-1]); vmcnt(2) in epilogue.
__global__ __launch_bounds__(256) void attn_kernel(
    const u16* __restrict__ Q,
    const u16* __restrict__ Km,
    const u16* __restrict__ VT,
    u16* __restrict__ aout)
{
    __shared__ u16 Ks[2][64 * 64];   // [key][dk], 16B chunks XOR-swizzled by (key&7)
    __shared__ u16 Vs[2][64 * 64];   // [dk][key], 16B chunks XOR-swizzled by (dk&7)
    __shared__ u16 Pl[4][16 * 64];   // per-wave P [qrow][key], 8B chunks XOR-swizzled
    const int t = threadIdx.x, wid = t >> 6, lane = t & 63;
    const int lr = lane & 15, lg = lane >> 4;
    const int bx = blockIdx.x;
    const int j = bx & 31;
    const int qb = 31 - (bx >> 5);                    // descending work: tail = tiny blocks
    const int bh = (j & 7) * 4 + (j >> 3);            // 4 heads per XCD
    const int b = bh >> 4, h = bh & 15;
    const int q0 = qb * 64;
    const int row0 = wid * 16;
    const int qw = q0 + row0;
    const int nkt = qb + 1;
    const int srow = lane >> 3, schunk = lane & 7;
    const int swz = (schunk ^ srow) << 3;

    const u16* Qg = Q  + (size_t)bh * SEQ * DK;
    const u16* Kg = Km + (size_t)bh * SEQ * DK;
    const u16* Vg = VT + (size_t)bh * DK * SEQ;
    u16* Plw = Pl[wid];

    bf16x8 aq[2];
    #pragma unroll
    for (int h2 = 0; h2 < 2; h2++)
        aq[h2] = *(const bf16x8*)&Qg[(qw + lr) * DK + h2 * 32 + lg * 8];

    float m_run = -__builtin_inff(), l_run = 0.0f;
    f32x4 acc[4];   // acc[dg]: O[qrow=qw+lr][d = dg*16+lg*4+r]
    #pragma unroll
    for (int dg = 0; dg < 4; dg++) acc[dg] = 0.0f;
    bf16x8 paR[2];  // P^T fragments of the PREVIOUS tile (carried across iterations)

    auto stageK = [&](int buf, int kb) {              // 2 gloads per wave
        const u16* ks = Kg + (size_t)(kb + row0 + srow) * DK + swz;
        gload16(ks,          &Ks[buf][row0 * 64]);
        gload16(ks + 8 * DK, &Ks[buf][(row0 + 8) * 64]);
    };
    auto stageV = [&](int buf, int kb) {              // 2 gloads per wave
        const u16* vs = Vg + (size_t)(row0 + srow) * SEQ + kb + swz;
        gload16(vs,                   &Vs[buf][row0 * 64]);
        gload16(vs + (size_t)8 * SEQ, &Vs[buf][(row0 + 8) * 64]);
    };

    stageK(0, 0);
    for (int kt = 0; kt < nkt; kt++) {
        __builtin_amdgcn_sched_barrier(0);
        __builtin_amdgcn_s_barrier();                 // raw: no vmcnt drain
        __builtin_amdgcn_sched_barrier(0);
        stageV(kt & 1, kt * 64);                      // V[kt] (consumed next iteration)
        stageK((kt + 1) & 1, (kt + 1 < nkt) ? (kt + 1) * 64 : 0);  // K[kt+1] (redundant on last)
        const int kb = kt * 64;

        // FIFO: oldest in flight = V[kt-1](2), K[kt](2); then V[kt](2), K[kt+1](2).
        asm volatile("s_waitcnt vmcnt(4)" ::: "memory");   // K[kt] AND V[kt-1] landed
        __builtin_amdgcn_sched_barrier(0);
        bf16x8 kf[4][2];
        #pragma unroll
        for (int kg = 0; kg < 4; kg++)
            #pragma unroll
            for (int h2 = 0; h2 < 2; h2++) {
                int row = kg * 16 + lr;
                kf[kg][h2] = *(const bf16x8*)&Ks[kt & 1][row * 64 + (((h2 * 4 + lg) ^ (lr & 7)) << 3)];
            }

        // S^T[key][qrow] = K . Q^T  (lane: qrow = lr, key = kg*16+lg*4+r)
        f32x4 sf[4];
        #pragma unroll
        for (int kg = 0; kg < 4; kg++) sf[kg] = 0.0f;
        __builtin_amdgcn_s_setprio(1);
        #pragma unroll
        for (int kg = 0; kg < 4; kg++) {
            sf[kg] = __builtin_amdgcn_mfma_f32_16x16x32_bf16(kf[kg][0], aq[0], sf[kg], 0, 0, 0);
            sf[kg] = __builtin_amdgcn_mfma_f32_16x16x32_bf16(kf[kg][1], aq[1], sf[kg], 0, 0, 0);
        }
        __builtin_amdgcn_s_setprio(0);

        if (kt) {
            // PV[kt-1]: independent of sf -> issues under SM's shadow; acc-rescale below
            // (program order) naturally waits for these MFMAs.
            const int vb = (kt - 1) & 1;
            __builtin_amdgcn_s_setprio(1);
            #pragma unroll
            for (int ck = 0; ck < 2; ck++)
                #pragma unroll
                for (int dg = 0; dg < 4; dg++) {
                    int row = dg * 16 + lr;
                    bf16x8 vf = *(const bf16x8*)&Vs[vb][row * 64 + (((ck * 4 + lg) ^ (lr & 7)) << 3)];
                    acc[dg] = __builtin_amdgcn_mfma_f32_16x16x32_bf16(vf, paR[ck], acc[dg], 0, 0, 0);
                }
            __builtin_amdgcn_s_setprio(0);
        }

        {
            if (kb + 64 > qw) {                       // diagonal band: mask
                const int qq = qw + lr;
                #pragma unroll
                for (int kg = 0; kg < 4; kg++)
                    #pragma unroll
                    for (int r = 0; r < 4; r++)
                        if (kb + kg * 16 + lg * 4 + r > qq) sf[kg][r] = -__builtin_inff();
            }
            float cmax = sf[0][0];
            #pragma unroll
            for (int kg = 0; kg < 4; kg++)
                #pragma unroll
                for (int r = 0; r < 4; r++) cmax = fmaxf(cmax, sf[kg][r]);
            if (!__all(cmax <= m_run + 8.0f)) {       // defer-max (log2 units)
                float mt = fmaxf(cmax, __shfl_xor(cmax, 16));
                mt = fmaxf(mt, __shfl_xor(mt, 32));
                float mn = fmaxf(m_run, mt);
                float scr = exp2f(m_run - mn);
                m_run = mn;
                l_run *= scr;
                #pragma unroll
                for (int dg = 0; dg < 4; dg++) acc[dg] *= scr;
            }
            float l = 0.0f;
            const int prow = lr * 64;
            #pragma unroll
            for (int kg = 0; kg < 4; kg++) {
                ushx4 pk;
                #pragma unroll
                for (int r = 0; r < 4; r++) {
                    float pv = exp2f(sf[kg][r] - m_run);
                    l += pv;
                    pk[r] = cbf(pv);
                }
                *(ushx4*)&Plw[prow + (((kg * 4 + lg) ^ ((lr & 7) << 1)) << 2)] = pk;
            }
            l_run += l;                               // per-lane partial (this lane's 16 keys)
        }

        asm volatile("s_waitcnt lgkmcnt(0)" ::: "memory");   // P writes done (same-wave DS order)
        __builtin_amdgcn_sched_barrier(0);
        #pragma unroll
        for (int ck = 0; ck < 2; ck++)
            paR[ck] = *(const bf16x8*)&Plw[lr * 64 + (((ck * 8 + lg * 2) ^ ((lr & 7) << 1)) << 2)];
    }

    // epilogue: PV[nkt-1]; V[nkt-1] still in flight (only K[nkt] behind it)
    asm volatile("s_waitcnt vmcnt(2)" ::: "memory");
    __builtin_amdgcn_sched_barrier(0);
    {
        const int vb = (nkt - 1) & 1;
        __builtin_amdgcn_s_setprio(1);
        #pragma unroll
        for (int ck = 0; ck < 2; ck++)
            #pragma unroll
            for (int dg = 0; dg < 4; dg++) {
                int row = dg * 16 + lr;
                bf16x8 vf = *(const bf16x8*)&Vs[vb][row * 64 + (((ck * 4 + lg) ^ (lr & 7)) << 3)];
                acc[dg] = __builtin_amdgcn_mfma_f32_16x16x32_bf16(vf, paR[ck], acc[dg], 0, 0, 0);
            }
        __builtin_amdgcn_s_setprio(0);
    }

    l_run += __shfl_xor(l_run, 16);
    l_run += __shfl_xor(l_run, 32);

    {
        float inv = 1.0f / l_run;
        int q = qw + lr;
        #pragma unroll
        for (int dg = 0; dg < 4; dg++) {
            ushx4 ow;
            #pragma unroll
            for (int r = 0; r < 4; r++) ow[r] = cbf(acc[dg][r] * inv);
            *(ushx4*)&aout[((size_t)b * SEQ + q) * D_MODEL + h * DK + dg * 16 + lg * 4] = ow;
        }
    }
}

extern "C" void kernel_launch(void* const* d_in, const int* in_sizes, int n_in,
                              void* d_out, int out_size, void* d_ws, size_t ws_size,
                              hipStream_t stream) {
    const float* x    = (const float*)d_in[0];
    const int*   tpos = (const int*)d_in[1];
    const float* Wq   = (const float*)d_in[2];
    const float* Wk   = (const float*)d_in[3];
    const float* Wv   = (const float*)d_in[4];
    const float* Wo   = (const float*)d_in[5];
    float* out = (float*)d_out;

    char* ws = (char*)d_ws;
    float2* cs = (float2*)ws;                                   // 512 KB
    u16* Qb   = (u16*)(ws + (512 << 10));                       // 8 MB
    u16* Kb   = (u16*)(ws + (512 << 10) + ((size_t)8  << 20));  // 8 MB
    u16* VT   = (u16*)(ws + (512 << 10) + ((size_t)16 << 20));  // 8 MB
    u16* xb   = (u16*)(ws + (512 << 10) + ((size_t)24 << 20));  // 8 MB (reused as attnb)
    u16* Wqb  = (u16*)(ws + (512 << 10) + ((size_t)32 << 20));  // 2 MB -- Wq/Wk contiguous
    u16* Wkb  = (u16*)(ws + (512 << 10) + ((size_t)34 << 20));
    u16* Wvb  = (u16*)(ws + (512 << 10) + ((size_t)36 << 20));
    u16* Wob  = (u16*)(ws + (512 << 10) + ((size_t)38 << 20));  // total 40.5 MB
    u16* attnb = xb;   // x no longer needed once QKV GEMMs are done (stream-ordered)

    prep_kernel<<<4352, 256, 0, stream>>>(x, Wq, Wk, Wv, Wo, xb, Wqb, Wkb, Wvb, Wob, cs);

    gemm_bt<0><<<dim3(32, 16), 256, 0, stream>>>(xb, Wqb, Qb, Kb, nullptr, tpos, cs);
    gemm_bt<3><<<dim3(32, 8),  256, 0, stream>>>(xb, Wvb, nullptr, nullptr, VT, tpos, cs);

    attn_kernel<<<1024, 256, 0, stream>>>(Qb, Kb, VT, attnb);

    gemm_bt<2><<<dim3(32, 8),  256, 0, stream>>>(attnb, Wob, nullptr, nullptr, out, tpos, cs);
}

// Round 16
// 119.728 us; speedup vs baseline: 1.2296x; 1.0332x over previous
//
#include <hip/hip_runtime.h>
#include <hip/hip_bf16.h>
#include <math.h>

#define D_MODEL 1024
#define NH      16
#define DK      64
#define SEQ     2048
#define BATCH   2

typedef float  f32x4  __attribute__((ext_vector_type(4)));
typedef __bf16 bf16x8 __attribute__((ext_vector_type(8)));
typedef unsigned short ushx4 __attribute__((ext_vector_type(4)));
typedef unsigned short ushx8 __attribute__((ext_vector_type(8)));
typedef unsigned short u16;

// RNE float->bf16 via compiler cast (single v_cvt on gfx950)
__device__ inline u16 cbf(float f) { __bf16 h = (__bf16)f; return *(u16*)&h; }

__device__ inline void gload16(const u16* g, u16* l) {
    // direct global->LDS DMA, 16B/lane, dest = wave-uniform base + lane*16
    __builtin_amdgcn_global_load_lds(
        (const __attribute__((address_space(1))) unsigned int*)g,
        (__attribute__((address_space(3))) unsigned int*)l,
        16, 0, 0);
}

// ---------------- fused prep: x/W fp32->bf16 + RoPE tables (1 launch) ----------------
__global__ void prep_kernel(const float* __restrict__ x,
                            const float* __restrict__ wq, const float* __restrict__ wk,
                            const float* __restrict__ wv, const float* __restrict__ wo,
                            u16* __restrict__ xb,
                            u16* __restrict__ wqb, u16* __restrict__ wkb,
                            u16* __restrict__ wvb, u16* __restrict__ wob,
                            float2* __restrict__ cs)
{
    const int bx = blockIdx.x, t = threadIdx.x;
    if (bx < 4096) {
        const float* in; u16* out; size_t base;
        if (bx < 2048) { in = x; out = xb; base = (size_t)bx * 2048; }
        else {
            int i = bx - 2048, sel = i >> 9;
            base = (size_t)(i & 511) * 2048;
            switch (sel) {
                case 0:  in = wq; out = wqb; break;
                case 1:  in = wk; out = wkb; break;
                case 2:  in = wv; out = wvb; break;
                default: in = wo; out = wob; break;
            }
        }
        size_t idx = base + (size_t)t * 8;
        f32x4 v0 = *(const f32x4*)(in + idx);
        f32x4 v1 = *(const f32x4*)(in + idx + 4);
        ushx4 o0, o1;
        #pragma unroll
        for (int e = 0; e < 4; e++) { o0[e] = cbf(v0[e]); o1[e] = cbf(v1[e]); }
        *(ushx4*)(out + idx) = o0;
        *(ushx4*)(out + idx + 4) = o1;
    } else {
        int i = (bx - 4096) * 256 + t;              // 2048*32 = 65536 total
        int pos = i >> 5, k = i & 31;
        float inv = powf(10000.0f, -2.0f * (float)k / 64.0f);
        float ang = (float)pos * inv;
        cs[i] = make_float2(cosf(ang), sinf(ang));
    }
}

// ---------------- GEMM body: C[m][n] = sum_k A[m][k] W[n][k], 2-phase dbuf (r9-proven) ----------------
// MODE 0: RoPE epilogue -> Qo (pre-scaled 0.125*log2e) / Ko (sel = n0>>10), bf16 [b][h][s][dk]
// MODE 2: fp32 out [m][n]
// MODE 3: swapped operands (rows=n, cols=m) -> coalesced V^T store, bf16 [b][h][dk][s]
template<int MODE>
__device__ __forceinline__ void gemm_body(
    const u16* __restrict__ A, const u16* __restrict__ W,
    u16* __restrict__ Qo, u16* __restrict__ Ko, void* __restrict__ Oo,
    const int* __restrict__ tpos, const float2* __restrict__ cs,
    const int m0, const int n0,
    u16 (&As)[2][128 * 32], u16 (&Bs)[2][128 * 32])
{
    constexpr int K = 1024;
    const int t  = threadIdx.x;
    const int lane = t & 63, wid = t >> 6;
    const int wm = wid >> 1, wn = wid & 1;       // 2x2 wave grid, 64x64 per wave
    const int lr = lane & 15, lg = lane >> 4;

    const int ldrow0 = wid * 32 + (lane >> 2);
    const int ldrow1 = ldrow0 + 16;
    const int lc = lane & 3;
    const u16* Asrc0 = A + (size_t)(m0 + ldrow0) * K + ((lc ^ ((ldrow0 >> 1) & 3)) << 3);
    const u16* Asrc1 = A + (size_t)(m0 + ldrow1) * K + ((lc ^ ((ldrow1 >> 1) & 3)) << 3);
    const u16* Bsrc0 = W + (size_t)(n0 + ldrow0) * K + ((lc ^ ((ldrow0 >> 1) & 3)) << 3);
    const u16* Bsrc1 = W + (size_t)(n0 + ldrow1) * K + ((lc ^ ((ldrow1 >> 1) & 3)) << 3);
    const int d0 = (wid * 32) * 32, d1 = (wid * 32 + 16) * 32;

    f32x4 acc[4][4];
    #pragma unroll
    for (int i = 0; i < 4; i++)
        #pragma unroll
        for (int j2 = 0; j2 < 4; j2++) acc[i][j2] = 0.0f;

    auto stage = [&](int buf, int k0) {
        gload16(Asrc0 + k0, &As[buf][d0]);
        gload16(Asrc1 + k0, &As[buf][d1]);
        gload16(Bsrc0 + k0, &Bs[buf][d0]);
        gload16(Bsrc1 + k0, &Bs[buf][d1]);
    };

    stage(0, 0);
    int buf = 0;
    for (int k0 = 0; k0 < K; k0 += 32) {
        __syncthreads();                 // drains my stage gloads + all waves' prev reads
        if (k0 + 32 < K) stage(buf ^ 1, k0 + 32);   // prefetch next tile

        bf16x8 af[4], bfr[4];
        #pragma unroll
        for (int mi = 0; mi < 4; mi++) {
            int row = wm * 64 + mi * 16 + lr;
            af[mi] = *(const bf16x8*)&As[buf][row * 32 + ((lg ^ ((row >> 1) & 3)) << 3)];
        }
        #pragma unroll
        for (int ni = 0; ni < 4; ni++) {
            int row = wn * 64 + ni * 16 + lr;
            bfr[ni] = *(const bf16x8*)&Bs[buf][row * 32 + ((lg ^ ((row >> 1) & 3)) << 3)];
        }
        #pragma unroll
        for (int mi = 0; mi < 4; mi++)
            #pragma unroll
            for (int ni = 0; ni < 4; ni++) {
                if constexpr (MODE == 3)
                    acc[mi][ni] = __builtin_amdgcn_mfma_f32_16x16x32_bf16(bfr[ni], af[mi], acc[mi][ni], 0, 0, 0);
                else
                    acc[mi][ni] = __builtin_amdgcn_mfma_f32_16x16x32_bf16(af[mi], bfr[ni], acc[mi][ni], 0, 0, 0);
            }
        buf ^= 1;
    }

    #pragma unroll
    for (int mi = 0; mi < 4; mi++)
        #pragma unroll
        for (int ni = 0; ni < 4; ni++) {
            f32x4 v4 = acc[mi][ni];
            #pragma unroll
            for (int r = 0; r < 4; r++) {
                float v = v4[r];
                if constexpr (MODE == 3) {
                    int n = n0 + wn * 64 + ni * 16 + lg * 4 + r;
                    int m = m0 + wm * 64 + mi * 16 + lr;
                    int h = n >> 6, d = n & 63;
                    int b = m >> 11, s = m & 2047;
                    ((u16*)Oo)[(((size_t)b * NH + h) * DK + d) * SEQ + s] = cbf(v);
                } else {
                    int m = m0 + wm * 64 + mi * 16 + lg * 4 + r;
                    int n = n0 + wn * 64 + ni * 16 + lr;
                    if constexpr (MODE == 2) {
                        ((float*)Oo)[(size_t)m * D_MODEL + n] = v;
                    } else {
                        int b = m >> 11, s = m & 2047;
                        int h = (n >> 6) & 15, d = n & 63;
                        float vp = __shfl_xor(v, 1);   // pair partner (n parity == lane parity)
                        int tp = tpos[s];
                        float2 c2 = cs[tp * 32 + (d >> 1)];
                        float res = (d & 1) ? (vp * c2.y + v * c2.x) : (v * c2.x - vp * c2.y);
                        const int sel = n0 >> 10;      // 0=Q (scaled), 1=K
                        if (sel == 0) res *= 0.18033688f;   // 0.125 * log2(e): softmax uses exp2
                        u16* outp = sel ? Ko : Qo;
                        outp[(((size_t)b * NH + h) * SEQ + s) * DK + d] = cbf(res);
                    }
                }
            }
        }
}

// ---------------- merged Q/K/V projection: grid (32, 24), branch OUTSIDE the K-loop ----------------
// y < 16: MODE 0 (Q/K from Wqk concat); y >= 16: MODE 3 (V^T from Wv). Block-uniform branch,
// two fully-specialized bodies (r11 lesson: never branch modes inside the hot loop).
__global__ __launch_bounds__(256) void gemm_qkv(
    const u16* __restrict__ xb, const u16* __restrict__ Wqk, const u16* __restrict__ Wv,
    u16* __restrict__ Qo, u16* __restrict__ Ko, u16* __restrict__ Vo,
    const int* __restrict__ tpos, const float2* __restrict__ cs)
{
    __shared__ u16 As[2][128 * 32];
    __shared__ u16 Bs[2][128 * 32];
    const int m0 = blockIdx.x * 128;
    if (blockIdx.y < 16)
        gemm_body<0>(xb, Wqk, Qo, Ko, nullptr, tpos, cs, m0, blockIdx.y * 128, As, Bs);
    else
        gemm_body<3>(xb, Wv, nullptr, nullptr, Vo, tpos, cs, m0, (blockIdx.y - 16) * 128, As, Bs);
}

// ---------------- output projection ----------------
__global__ __launch_bounds__(256) void gemm_out(
    const u16* __restrict__ A, const u16* __restrict__ W, float* __restrict__ outp,
    const int* __restrict__ tpos, const float2* __restrict__ cs)
{
    __shared__ u16 As[2][128 * 32];
    __shared__ u16 Bs[2][128 * 32];
    gemm_body<2>(A, W, nullptr, nullptr, outp, tpos, cs,
                 blockIdx.x * 128, blockIdx.y * 128, As, Bs);
}

// ---------------- causal flash attention, QBLK=64, PV pipelined one tile back (r15: 50 us) ----------------
// Q bf16 [b][h][s][dk] PRE-SCALED by 0.125*log2e; K bf16 [b][h][s][dk]; VT bf16 [b][h][dk][s].
// Block = 64 q-rows of one (b,h); wave w owns rows qw..qw+15. Grid 1024 = 32 qb x 32 bh.
// qb = 31-(bx>>5) descending; bh = (bx&7)*4 + ((bx>>3)&3) -> 4 heads/XCD (L2-resident).
// Swapped softmax: S^T = mfma(K, Q); O^T = mfma(V^T, P^T).
// K dbuf + V dbuf (40 KB LDS). Body kt: QK[kt], PV[kt-1] (paR regs + Vs[(kt-1)&1]), SM[kt].
// One vmcnt(4)/tile (FIFO: draining K[kt] also drains V[kt-1]); vmcnt(2) in epilogue.
__global__ __launch_bounds__(256) void attn_kernel(
    const u16* __restrict__ Q,
    const u16* __restrict__ Km,
    const u16* __restrict__ VT,
    u16* __restrict__ aout)
{
    __shared__ u16 Ks[2][64 * 64];   // [key][dk], 16B chunks XOR-swizzled by (key&7)
    __shared__ u16 Vs[2][64 * 64];   // [dk][key], 16B chunks XOR-swizzled by (dk&7)
    __shared__ u16 Pl[4][16 * 64];   // per-wave P [qrow][key], 8B chunks XOR-swizzled
    const int t = threadIdx.x, wid = t >> 6, lane = t & 63;
    const int lr = lane & 15, lg = lane >> 4;
    const int bx = blockIdx.x;
    const int j = bx & 31;
    const int qb = 31 - (bx >> 5);                    // descending work: tail = tiny blocks
    const int bh = (j & 7) * 4 + (j >> 3);            // 4 heads per XCD
    const int b = bh >> 4, h = bh & 15;
    const int q0 = qb * 64;
    const int row0 = wid * 16;
    const int qw = q0 + row0;
    const int nkt = qb + 1;
    const int srow = lane >> 3, schunk = lane & 7;
    const int swz = (schunk ^ srow) << 3;

    const u16* Qg = Q  + (size_t)bh * SEQ * DK;
    const u16* Kg = Km + (size_t)bh * SEQ * DK;
    const u16* Vg = VT + (size_t)bh * DK * SEQ;
    u16* Plw = Pl[wid];

    bf16x8 aq[2];
    #pragma unroll
    for (int h2 = 0; h2 < 2; h2++)
        aq[h2] = *(const bf16x8*)&Qg[(qw + lr) * DK + h2 * 32 + lg * 8];

    float m_run = -__builtin_inff(), l_run = 0.0f;
    f32x4 acc[4];   // acc[dg]: O[qrow=qw+lr][d = dg*16+lg*4+r]
    #pragma unroll
    for (int dg = 0; dg < 4; dg++) acc[dg] = 0.0f;
    bf16x8 paR[2];  // P^T fragments of the PREVIOUS tile (carried across iterations)

    auto stageK = [&](int buf, int kb) {              // 2 gloads per wave
        const u16* ks = Kg + (size_t)(kb + row0 + srow) * DK + swz;
        gload16(ks,          &Ks[buf][row0 * 64]);
        gload16(ks + 8 * DK, &Ks[buf][(row0 + 8) * 64]);
    };
    auto stageV = [&](int buf, int kb) {              // 2 gloads per wave
        const u16* vs = Vg + (size_t)(row0 + srow) * SEQ + kb + swz;
        gload16(vs,                   &Vs[buf][row0 * 64]);
        gload16(vs + (size_t)8 * SEQ, &Vs[buf][(row0 + 8) * 64]);
    };

    stageK(0, 0);
    for (int kt = 0; kt < nkt; kt++) {
        __builtin_amdgcn_sched_barrier(0);
        __builtin_amdgcn_s_barrier();                 // raw: no vmcnt drain
        __builtin_amdgcn_sched_barrier(0);
        stageV(kt & 1, kt * 64);                      // V[kt] (consumed next iteration)
        stageK((kt + 1) & 1, (kt + 1 < nkt) ? (kt + 1) * 64 : 0);  // K[kt+1] (redundant on last)
        const int kb = kt * 64;

        // FIFO: oldest in flight = V[kt-1](2), K[kt](2); then V[kt](2), K[kt+1](2).
        asm volatile("s_waitcnt vmcnt(4)" ::: "memory");   // K[kt] AND V[kt-1] landed
        __builtin_amdgcn_sched_barrier(0);
        bf16x8 kf[4][2];
        #pragma unroll
        for (int kg = 0; kg < 4; kg++)
            #pragma unroll
            for (int h2 = 0; h2 < 2; h2++) {
                int row = kg * 16 + lr;
                kf[kg][h2] = *(const bf16x8*)&Ks[kt & 1][row * 64 + (((h2 * 4 + lg) ^ (lr & 7)) << 3)];
            }

        // S^T[key][qrow] = K . Q^T  (lane: qrow = lr, key = kg*16+lg*4+r)
        f32x4 sf[4];
        #pragma unroll
        for (int kg = 0; kg < 4; kg++) sf[kg] = 0.0f;
        __builtin_amdgcn_s_setprio(1);
        #pragma unroll
        for (int kg = 0; kg < 4; kg++) {
            sf[kg] = __builtin_amdgcn_mfma_f32_16x16x32_bf16(kf[kg][0], aq[0], sf[kg], 0, 0, 0);
            sf[kg] = __builtin_amdgcn_mfma_f32_16x16x32_bf16(kf[kg][1], aq[1], sf[kg], 0, 0, 0);
        }
        __builtin_amdgcn_s_setprio(0);

        if (kt) {
            // PV[kt-1]: independent of sf -> issues under SM's shadow; acc-rescale below
            // (program order) naturally waits for these MFMAs.
            const int vb = (kt - 1) & 1;
            __builtin_amdgcn_s_setprio(1);
            #pragma unroll
            for (int ck = 0; ck < 2; ck++)
                #pragma unroll
                for (int dg = 0; dg < 4; dg++) {
                    int row = dg * 16 + lr;
                    bf16x8 vf = *(const bf16x8*)&Vs[vb][row * 64 + (((ck * 4 + lg) ^ (lr & 7)) << 3)];
                    acc[dg] = __builtin_amdgcn_mfma_f32_16x16x32_bf16(vf, paR[ck], acc[dg], 0, 0, 0);
                }
            __builtin_amdgcn_s_setprio(0);
        }

        {
            if (kb + 64 > qw) {                       // diagonal band: mask
                const int qq = qw + lr;
                #pragma unroll
                for (int kg = 0; kg < 4; kg++)
                    #pragma unroll
                    for (int r = 0; r < 4; r++)
                        if (kb + kg * 16 + lg * 4 + r > qq) sf[kg][r] = -__builtin_inff();
            }
            float cmax = sf[0][0];
            #pragma unroll
            for (int kg = 0; kg < 4; kg++)
                #pragma unroll
                for (int r = 0; r < 4; r++) cmax = fmaxf(cmax, sf[kg][r]);
            if (!__all(cmax <= m_run + 8.0f)) {       // defer-max (log2 units)
                float mt = fmaxf(cmax, __shfl_xor(cmax, 16));
                mt = fmaxf(mt, __shfl_xor(mt, 32));
                float mn = fmaxf(m_run, mt);
                float scr = exp2f(m_run - mn);
                m_run = mn;
                l_run *= scr;
                #pragma unroll
                for (int dg = 0; dg < 4; dg++) acc[dg] *= scr;
            }
            float l = 0.0f;
            const int prow = lr * 64;
            #pragma unroll
            for (int kg = 0; kg < 4; kg++) {
                ushx4 pk;
                #pragma unroll
                for (int r = 0; r < 4; r++) {
                    float pv = exp2f(sf[kg][r] - m_run);
                    l += pv;
                    pk[r] = cbf(pv);
                }
                *(ushx4*)&Plw[prow + (((kg * 4 + lg) ^ ((lr & 7) << 1)) << 2)] = pk;
            }
            l_run += l;                               // per-lane partial (this lane's 16 keys)
        }

        asm volatile("s_waitcnt lgkmcnt(0)" ::: "memory");   // P writes done (same-wave DS order)
        __builtin_amdgcn_sched_barrier(0);
        #pragma unroll
        for (int ck = 0; ck < 2; ck++)
            paR[ck] = *(const bf16x8*)&Plw[lr * 64 + (((ck * 8 + lg * 2) ^ ((lr & 7) << 1)) << 2)];
    }

    // epilogue: PV[nkt-1]; V[nkt-1] still in flight (only K[nkt] behind it)
    asm volatile("s_waitcnt vmcnt(2)" ::: "memory");
    __builtin_amdgcn_sched_barrier(0);
    {
        const int vb = (nkt - 1) & 1;
        __builtin_amdgcn_s_setprio(1);
        #pragma unroll
        for (int ck = 0; ck < 2; ck++)
            #pragma unroll
            for (int dg = 0; dg < 4; dg++) {
                int row = dg * 16 + lr;
                bf16x8 vf = *(const bf16x8*)&Vs[vb][row * 64 + (((ck * 4 + lg) ^ (lr & 7)) << 3)];
                acc[dg] = __builtin_amdgcn_mfma_f32_16x16x32_bf16(vf, paR[ck], acc[dg], 0, 0, 0);
            }
        __builtin_amdgcn_s_setprio(0);
    }

    l_run += __shfl_xor(l_run, 16);
    l_run += __shfl_xor(l_run, 32);

    {
        float inv = 1.0f / l_run;
        int q = qw + lr;
        #pragma unroll
        for (int dg = 0; dg < 4; dg++) {
            ushx4 ow;
            #pragma unroll
            for (int r = 0; r < 4; r++) ow[r] = cbf(acc[dg][r] * inv);
            *(ushx4*)&aout[((size_t)b * SEQ + q) * D_MODEL + h * DK + dg * 16 + lg * 4] = ow;
        }
    }
}

extern "C" void kernel_launch(void* const* d_in, const int* in_sizes, int n_in,
                              void* d_out, int out_size, void* d_ws, size_t ws_size,
                              hipStream_t stream) {
    const float* x    = (const float*)d_in[0];
    const int*   tpos = (const int*)d_in[1];
    const float* Wq   = (const float*)d_in[2];
    const float* Wk   = (const float*)d_in[3];
    const float* Wv   = (const float*)d_in[4];
    const float* Wo   = (const float*)d_in[5];
    float* out = (float*)d_out;

    char* ws = (char*)d_ws;
    float2* cs = (float2*)ws;                                   // 512 KB
    u16* Qb   = (u16*)(ws + (512 << 10));                       // 8 MB
    u16* Kb   = (u16*)(ws + (512 << 10) + ((size_t)8  << 20));  // 8 MB
    u16* VT   = (u16*)(ws + (512 << 10) + ((size_t)16 << 20));  // 8 MB
    u16* xb   = (u16*)(ws + (512 << 10) + ((size_t)24 << 20));  // 8 MB (reused as attnb)
    u16* Wqb  = (u16*)(ws + (512 << 10) + ((size_t)32 << 20));  // 2 MB -- Wq/Wk contiguous
    u16* Wkb  = (u16*)(ws + (512 << 10) + ((size_t)34 << 20));
    u16* Wvb  = (u16*)(ws + (512 << 10) + ((size_t)36 << 20));
    u16* Wob  = (u16*)(ws + (512 << 10) + ((size_t)38 << 20));  // total 40.5 MB
    u16* attnb = xb;   // x no longer needed once QKV GEMMs are done (stream-ordered)

    prep_kernel<<<4352, 256, 0, stream>>>(x, Wq, Wk, Wv, Wo, xb, Wqb, Wkb, Wvb, Wob, cs);

    gemm_qkv<<<dim3(32, 24), 256, 0, stream>>>(xb, Wqb, Wvb, Qb, Kb, VT, tpos, cs);

    attn_kernel<<<1024, 256, 0, stream>>>(Qb, Kb, VT, attnb);

    gemm_out<<<dim3(32, 8), 256, 0, stream>>>(attnb, Wob, out, tpos, cs);
}